// Round 6
// baseline (2405.689 us; speedup 1.0000x reference)
//
#include <hip/hip_runtime.h>
#include <stdint.h>

#define BB 16
#define TT 4096
#define CC 8
#define FF 64
#define KW 11
#define LL 4096

typedef __attribute__((ext_vector_type(8))) short short8;
typedef __attribute__((ext_vector_type(16))) float floatx16;

__device__ __forceinline__ unsigned short f2b(float f) {
    union { float f; uint32_t i; } v; v.f = f;
    uint32_t x = v.i;
    return (unsigned short)((x + 0x7fffu + ((x >> 16) & 1u)) >> 16);  // RNE
}
__device__ __forceinline__ float b2f(unsigned short u) {
    union { uint32_t i; float f; } v; v.i = ((uint32_t)u) << 16; return v.f;
}
// pack fp32 -> (hi bf16 in low16) | (residual-lo bf16 in high16)
__device__ __forceinline__ uint32_t packsplit(float v) {
    unsigned short hi = f2b(v);
    unsigned short lo = f2b(v - b2f(hi));
    return (uint32_t)hi | ((uint32_t)lo << 16);
}
__device__ __forceinline__ short8 mk8(uint32_t a, uint32_t b, uint32_t c, uint32_t d) {
    union { uint32_t u[4]; short8 s; } r;
    r.u[0] = a; r.u[1] = b; r.u[2] = c; r.u[3] = d; return r.s;
}
__device__ __forceinline__ short8 mk_hi(uint4 q0, uint4 q1) {
    return mk8((q0.x & 0xffffu) | (q0.y << 16), (q0.z & 0xffffu) | (q0.w << 16),
               (q1.x & 0xffffu) | (q1.y << 16), (q1.z & 0xffffu) | (q1.w << 16));
}
__device__ __forceinline__ short8 mk_lo(uint4 q0, uint4 q1) {
    return mk8((q0.x >> 16) | (q0.y & 0xffff0000u), (q0.z >> 16) | (q0.w & 0xffff0000u),
               (q1.x >> 16) | (q1.y & 0xffff0000u), (q1.z >> 16) | (q1.w & 0xffff0000u));
}

#define L2E 1.4426950408889634f

// ------- Kernel 0: W -> packed hi/lo bf16 transposed [l][k]; db -> -db*log2e -------
__global__ __launch_bounds__(256) void k_split(
        const float* __restrict__ dw, const float* __restrict__ db,
        uint32_t* __restrict__ Wt, float* __restrict__ dbc) {
    const int idx = blockIdx.x * 256 + threadIdx.x;   // 262144
    const int k = idx >> 12, l = idx & (LL - 1);
    Wt[l * 64 + k] = packsplit(dw[idx]);
    if (idx < LL) dbc[idx] = -db[idx] * L2E;
}

// ------- Kernel 1: conv1d + BN + exp -> sumexp[b,f] --------------------------------
__global__ __launch_bounds__(256) void k_sumexp(
        const float* __restrict__ x, const float* __restrict__ cw,
        const float* __restrict__ cb, const float* __restrict__ gm,
        const float* __restrict__ bt, const float* __restrict__ mn,
        const float* __restrict__ vr, float* __restrict__ sumexp) {
    __shared__ float wsm[KW * CC * FF];
    __shared__ float xs[(64 + KW - 1) * CC];
    __shared__ float red[4 * FF];
    const int tid = threadIdx.x;
    const int b  = blockIdx.x / (TT / 64);
    const int t0 = (blockIdx.x % (TT / 64)) * 64;

    for (int i = tid; i < KW * CC * FF; i += 256) wsm[i] = cw[i];
    for (int i = tid; i < (64 + KW - 1) * CC; i += 256) {
        int row = i / CC, c = i % CC;
        int t = t0 - (KW / 2) + row;
        xs[i] = (t >= 0 && t < TT) ? x[((size_t)b * TT + t) * CC + c] : 0.0f;
    }
    const int f = tid & 63, ts = tid >> 6;
    const float s  = gm[f] * rsqrtf(vr[f] + 1e-3f);
    const float bb = bt[f] + (cb[f] - mn[f]) * s;
    __syncthreads();

    float esum = 0.f;
    for (int tt = ts; tt < 64; tt += 4) {
        float acc = 0.f;
#pragma unroll
        for (int k = 0; k < KW; ++k)
#pragma unroll
            for (int c = 0; c < CC; ++c)
                acc = fmaf(xs[(tt + k) * CC + c], wsm[(k * CC + c) * FF + f], acc);
        esum += __expf(fmaf(acc, s, bb));
    }
    red[ts * FF + f] = esum;
    __syncthreads();
    if (ts == 0) {
        float tot = red[f] + red[FF + f] + red[2 * FF + f] + red[3 * FF + f];
        atomicAdd(&sumexp[b * FF + f], tot);
    }
}

// ------- Kernel 2: conv+softmax+pos -> split-bf16 MFMA GEMM -> sigma-sum -----------
// Block = (b, 64-t tile), 1024 blocks -> target 4 blocks/CU. LDS padded to 40 KB so
// LDS-occupancy bound == 4 blocks/CU (keeps the VGPR allocator targeting 4 waves/EU;
// (256,4) + small LDS made it target 64 VGPRs -> 2.9 GB scratch spills in round 5).
__global__ __launch_bounds__(256) void k_main(
        const float* __restrict__ x,  const float* __restrict__ cw,
        const float* __restrict__ cb, const float* __restrict__ gm,
        const float* __restrict__ bt, const float* __restrict__ mn,
        const float* __restrict__ vr, const uint32_t* __restrict__ Wt,
        const float* __restrict__ dbc, const float* __restrict__ sumexp,
        float* __restrict__ shiftsum) {
    __shared__ uint32_t smem[10240];           // 40960 B (union + occupancy pad)
    float* xs  = (float*)smem;                 // 592 floats   (conv phase)
    float* wsm = (float*)smem + 592;           // 5632 floats  (conv phase)
    uint32_t* Asp = smem;                      // 64*68 = 4352 dwords (gemm phase)

    const int tid = threadIdx.x;
    const int b  = blockIdx.y;
    const int t0 = blockIdx.x * 64;

    for (int i = tid; i < KW * CC * FF; i += 256) wsm[i] = cw[i];
    for (int i = tid; i < (64 + KW - 1) * CC; i += 256) {
        int row = i / CC, c = i % CC;
        int t = t0 - (KW / 2) + row;
        xs[i] = (t >= 0 && t < TT) ? x[((size_t)b * TT + t) * CC + c] : 0.0f;
    }
    const int f = tid & 63, tq = tid >> 6;
    const float s  = gm[f] * rsqrtf(vr[f] + 1e-3f);
    const float bbv = bt[f] + (cb[f] - mn[f]) * s;
    const float inv_se = 1.0f / sumexp[b * FF + f];
    const float tsf = exp2f(-0.20762050586796017f * (float)(f & ~1));
    __syncthreads();

    uint32_t packed[16];
#pragma unroll
    for (int i = 0; i < 16; ++i) {
        const int tt = tq + 4 * i;
        float acc = 0.f;
#pragma unroll
        for (int k = 0; k < KW; ++k)
#pragma unroll
            for (int c = 0; c < CC; ++c)
                acc = fmaf(xs[(tt + k) * CC + c], wsm[(k * CC + c) * FF + f], acc);
        float e = __expf(fmaf(acc, s, bbv));
        float ang = (float)(t0 + tt) * tsf;
        float p = (f & 1) ? cosf(ang) : sinf(ang);
        packed[i] = packsplit(fmaf(e, inv_se, p));
    }
    __syncthreads();   // conv reads of xs/wsm done -> safe to overwrite with Asp
#pragma unroll
    for (int i = 0; i < 16; ++i) Asp[(tq + 4 * i) * 68 + f] = packed[i];
    __syncthreads();   // Asp visible

    const int lane = tid & 63;
    const int wv   = tid >> 6;
    const int half = lane >> 5;
    const int ln31 = lane & 31;

    for (int lt = 0; lt < 32; ++lt) {
        const int lbase = lt * 128 + wv * 32;
        const uint32_t* wp = Wt + (size_t)(lbase + ln31) * 64 + half * 8;
        short8 Whi[4], Wlo[4];
#pragma unroll
        for (int kf = 0; kf < 4; ++kf) {
            uint4 q0 = *reinterpret_cast<const uint4*>(wp + kf * 16);
            uint4 q1 = *reinterpret_cast<const uint4*>(wp + kf * 16 + 4);
            Whi[kf] = mk_hi(q0, q1);
            Wlo[kf] = mk_lo(q0, q1);
        }
        float dbv[16], sumsig[16];
#pragma unroll
        for (int r = 0; r < 16; ++r) {
            dbv[r] = dbc[lbase + 4 * half + (r & 3) + 8 * (r >> 2)];
            sumsig[r] = 0.f;
        }
        for (int nt = 0; nt < 2; ++nt) {
            floatx16 acc = {0.f, 0.f, 0.f, 0.f, 0.f, 0.f, 0.f, 0.f,
                            0.f, 0.f, 0.f, 0.f, 0.f, 0.f, 0.f, 0.f};
            const uint32_t* ap = Asp + (nt * 32 + ln31) * 68 + half * 8;
#pragma unroll
            for (int kf = 0; kf < 4; ++kf) {
                uint4 q0 = *reinterpret_cast<const uint4*>(ap + kf * 16);
                uint4 q1 = *reinterpret_cast<const uint4*>(ap + kf * 16 + 4);
                short8 Bhi = mk_hi(q0, q1);
                short8 Blo = mk_lo(q0, q1);
                acc = __builtin_amdgcn_mfma_f32_32x32x16_bf16(Whi[kf], Bhi, acc, 0, 0, 0);
                acc = __builtin_amdgcn_mfma_f32_32x32x16_bf16(Whi[kf], Blo, acc, 0, 0, 0);
                acc = __builtin_amdgcn_mfma_f32_32x32x16_bf16(Wlo[kf], Bhi, acc, 0, 0, 0);
            }
#pragma unroll
            for (int r = 0; r < 16; ++r) {
                // sigma(z+db) = rcp(1 + exp2(-(z+db)*log2e))
                float e = __builtin_amdgcn_exp2f(fmaf(acc[r], -L2E, dbv[r]));
                sumsig[r] += __builtin_amdgcn_rcpf(1.0f + e);
            }
        }
#pragma unroll
        for (int r = 0; r < 16; ++r) {
            float v = sumsig[r];
            v += __shfl_xor(v, 1, 32);
            v += __shfl_xor(v, 2, 32);
            v += __shfl_xor(v, 4, 32);
            v += __shfl_xor(v, 8, 32);
            v += __shfl_xor(v, 16, 32);
            sumsig[r] = v;
        }
        if (ln31 == 0) {
            float* dst = shiftsum + (size_t)b * LL + lbase + 4 * half;
#pragma unroll
            for (int r = 0; r < 16; ++r)
                atomicAdd(dst + (r & 3) + 8 * (r >> 2), sumsig[r]);
        }
    }
}

// ------- Kernel 3: truncated Gaussian warp (shift = 2*S - T) -----------------------
__global__ __launch_bounds__(256) void k_warp(
        const float* __restrict__ shiftsum, const float* __restrict__ x,
        float* __restrict__ out) {
    const int idx = blockIdx.x * 256 + threadIdx.x;  // = b*L + l
    const int l = idx & (LL - 1);
    const int b = idx >> 12;
    const float sh = fmaf(2.0f, shiftsum[idx], -(float)TT);
    const float scale = (float)TT / (float)LL;
    const float center = ((float)(l + 1) + sh) * scale;
    const float R = 7.0f;
    int tlo = (int)ceilf(center - 1.0f - R);
    int thi = (int)floorf(center - 1.0f + R);
    if (tlo < 0) tlo = 0;
    if (thi > TT - 1) thi = TT - 1;
    float acc[CC];
#pragma unroll
    for (int c = 0; c < CC; ++c) acc[c] = 0.f;
    const float inv_amp = (float)(1.0 / 1.772637204826652);
    for (int t = tlo; t <= thi; ++t) {
        float d = (float)(t + 1) - center;
        float w = __expf(-d * d) * inv_amp;   // WIDTH = 1
        const float4 x0 = *reinterpret_cast<const float4*>(x + ((size_t)b * TT + t) * CC);
        const float4 x1 = *reinterpret_cast<const float4*>(x + ((size_t)b * TT + t) * CC + 4);
        acc[0] = fmaf(w, x0.x, acc[0]);
        acc[1] = fmaf(w, x0.y, acc[1]);
        acc[2] = fmaf(w, x0.z, acc[2]);
        acc[3] = fmaf(w, x0.w, acc[3]);
        acc[4] = fmaf(w, x1.x, acc[4]);
        acc[5] = fmaf(w, x1.y, acc[5]);
        acc[6] = fmaf(w, x1.z, acc[6]);
        acc[7] = fmaf(w, x1.w, acc[7]);
    }
    float* o = out + (size_t)idx * CC;
    *reinterpret_cast<float4*>(o)     = make_float4(acc[0], acc[1], acc[2], acc[3]);
    *reinterpret_cast<float4*>(o + 4) = make_float4(acc[4], acc[5], acc[6], acc[7]);
}

extern "C" void kernel_launch(void* const* d_in, const int* in_sizes, int n_in,
                              void* d_out, int out_size, void* d_ws, size_t ws_size,
                              hipStream_t stream) {
    const float* x  = (const float*)d_in[0];
    const float* cw = (const float*)d_in[1];
    const float* cb = (const float*)d_in[2];
    const float* gm = (const float*)d_in[3];
    const float* bt = (const float*)d_in[4];
    const float* mn = (const float*)d_in[5];
    const float* vr = (const float*)d_in[6];
    const float* dw = (const float*)d_in[7];
    const float* db = (const float*)d_in[8];

    float* sumexp    = (float*)d_ws;                       // 1024 floats
    float* shiftsum  = sumexp + BB * FF;                   // 65536 floats
    uint32_t* Wt     = (uint32_t*)(shiftsum + BB * LL);    // 262144 dwords (1 MB)
    float* dbc       = (float*)(Wt + FF * LL);             // 4096 floats

    hipMemsetAsync(sumexp, 0, (size_t)(BB * FF + BB * LL) * sizeof(float), stream);

    k_split<<<(FF * LL) / 256, 256, 0, stream>>>(dw, db, Wt, dbc);
    k_sumexp<<<BB * (TT / 64), 256, 0, stream>>>(x, cw, cb, gm, bt, mn, vr, sumexp);
    k_main<<<dim3(TT / 64, BB), 256, 0, stream>>>(x, cw, cb, gm, bt, mn, vr,
                                                  Wt, dbc, sumexp, shiftsum);
    k_warp<<<(BB * LL) / 256, 256, 0, stream>>>(shiftsum, x, (float*)d_out);
}

// Round 7
// 671.756 us; speedup vs baseline: 3.5812x; 3.5812x over previous
//
#include <hip/hip_runtime.h>
#include <stdint.h>

#define BB 16
#define TT 4096
#define CC 8
#define FF 64
#define KW 11
#define LL 4096

typedef __attribute__((ext_vector_type(8))) short short8;
typedef __attribute__((ext_vector_type(16))) float floatx16;

__device__ __forceinline__ unsigned short f2b(float f) {
    union { float f; uint32_t i; } v; v.f = f;
    uint32_t x = v.i;
    return (unsigned short)((x + 0x7fffu + ((x >> 16) & 1u)) >> 16);  // RNE
}
__device__ __forceinline__ float b2f(unsigned short u) {
    union { uint32_t i; float f; } v; v.i = ((uint32_t)u) << 16; return v.f;
}
// pack fp32 -> (hi bf16 in low16) | (residual-lo bf16 in high16)
__device__ __forceinline__ uint32_t packsplit(float v) {
    unsigned short hi = f2b(v);
    unsigned short lo = f2b(v - b2f(hi));
    return (uint32_t)hi | ((uint32_t)lo << 16);
}
__device__ __forceinline__ short8 mk8(uint32_t a, uint32_t b, uint32_t c, uint32_t d) {
    union { uint32_t u[4]; short8 s; } r;
    r.u[0] = a; r.u[1] = b; r.u[2] = c; r.u[3] = d; return r.s;
}
__device__ __forceinline__ short8 mk_hi(uint4 q0, uint4 q1) {
    return mk8((q0.x & 0xffffu) | (q0.y << 16), (q0.z & 0xffffu) | (q0.w << 16),
               (q1.x & 0xffffu) | (q1.y << 16), (q1.z & 0xffffu) | (q1.w << 16));
}
__device__ __forceinline__ short8 mk_lo(uint4 q0, uint4 q1) {
    return mk8((q0.x >> 16) | (q0.y & 0xffff0000u), (q0.z >> 16) | (q0.w & 0xffff0000u),
               (q1.x >> 16) | (q1.y & 0xffff0000u), (q1.z >> 16) | (q1.w & 0xffff0000u));
}

// ------- Kernel 0: W fp32 [64][4096] -> packed hi/lo bf16, transposed [l][k] -------
__global__ __launch_bounds__(256) void k_split(
        const float* __restrict__ dw, uint32_t* __restrict__ Wt) {
    const int idx = blockIdx.x * 256 + threadIdx.x;   // 262144
    const int k = idx >> 12, l = idx & (LL - 1);
    Wt[l * 64 + k] = packsplit(dw[idx]);
}

// ------- Kernel 1: conv1d + BN + exp -> sumexp[b,f] --------------------------------
__global__ __launch_bounds__(256) void k_sumexp(
        const float* __restrict__ x, const float* __restrict__ cw,
        const float* __restrict__ cb, const float* __restrict__ gm,
        const float* __restrict__ bt, const float* __restrict__ mn,
        const float* __restrict__ vr, float* __restrict__ sumexp) {
    __shared__ float wsm[KW * CC * FF];
    __shared__ float xs[(64 + KW - 1) * CC];
    __shared__ float red[4 * FF];
    const int tid = threadIdx.x;
    const int b  = blockIdx.x / (TT / 64);
    const int t0 = (blockIdx.x % (TT / 64)) * 64;

    for (int i = tid; i < KW * CC * FF; i += 256) wsm[i] = cw[i];
    for (int i = tid; i < (64 + KW - 1) * CC; i += 256) {
        int row = i / CC, c = i % CC;
        int t = t0 - (KW / 2) + row;
        xs[i] = (t >= 0 && t < TT) ? x[((size_t)b * TT + t) * CC + c] : 0.0f;
    }
    const int f = tid & 63, ts = tid >> 6;
    const float s  = gm[f] * rsqrtf(vr[f] + 1e-3f);
    const float bb = bt[f] + (cb[f] - mn[f]) * s;
    __syncthreads();

    float esum = 0.f;
    for (int tt = ts; tt < 64; tt += 4) {
        float acc = 0.f;
#pragma unroll
        for (int k = 0; k < KW; ++k)
#pragma unroll
            for (int c = 0; c < CC; ++c)
                acc = fmaf(xs[(tt + k) * CC + c], wsm[(k * CC + c) * FF + f], acc);
        esum += __expf(fmaf(acc, s, bb));
    }
    red[ts * FF + f] = esum;
    __syncthreads();
    if (ts == 0) {
        float tot = red[f] + red[FF + f] + red[2 * FF + f] + red[3 * FF + f];
        atomicAdd(&sumexp[b * FF + f], tot);
    }
}

// ------- Kernel 2: conv+softmax+pos -> split-bf16 MFMA GEMM -> sigma-sum -----------
// Round-4 main loop verbatim (known-good codegen: 124 VGPR, no spills).
// Deltas vs round 4: (a) blockIdx.z splits the 32 l-tiles into 2x16 -> grid 1024;
// (b) conv scratch unions into Asp via packed[32] register buffer (one-time, pre-loop);
// (c) dense bias folded into MFMA C-init (acc[r]=dbv[r]) -> dbs LDS mirror dropped.
// LDS 34816 B -> up to 4 blocks/CU; grid 1024 = 4 blocks/CU of work.
__global__ __launch_bounds__(256) void k_main(
        const float* __restrict__ x,  const float* __restrict__ cw,
        const float* __restrict__ cb, const float* __restrict__ gm,
        const float* __restrict__ bt, const float* __restrict__ mn,
        const float* __restrict__ vr, const uint32_t* __restrict__ Wt,
        const float* __restrict__ db, const float* __restrict__ sumexp,
        float* __restrict__ shiftsum) {
    __shared__ uint32_t smem[128 * 68];        // 34816 B; union{conv scratch, Asp}
    float* xs  = (float*)smem;                 // 1104 floats  (conv phase)
    float* wsm = (float*)smem + 1104;          // 5632 floats  (conv phase)
    uint32_t* Asp = smem;                      // Asp[t][f], stride 68 (gemm phase)

    const int tid = threadIdx.x;
    const int b   = blockIdx.y;
    const int t0  = blockIdx.x * 128;
    const int lt0 = blockIdx.z * 16;

    for (int i = tid; i < KW * CC * FF; i += 256) wsm[i] = cw[i];
    for (int i = tid; i < (128 + KW - 1) * CC; i += 256) {
        int row = i / CC, c = i % CC;
        int t = t0 - (KW / 2) + row;
        xs[i] = (t >= 0 && t < TT) ? x[((size_t)b * TT + t) * CC + c] : 0.0f;
    }
    const int f = tid & 63, tq = tid >> 6;
    const float s  = gm[f] * rsqrtf(vr[f] + 1e-3f);
    const float bbv = bt[f] + (cb[f] - mn[f]) * s;
    const float inv_se = 1.0f / sumexp[b * FF + f];
    const float tsf = exp2f(-0.20762050586796017f * (float)(f & ~1));
    __syncthreads();

    uint32_t packed[32];
#pragma unroll
    for (int i = 0; i < 32; ++i) {
        const int tt = tq + 4 * i;
        float acc = 0.f;
#pragma unroll
        for (int k = 0; k < KW; ++k)
#pragma unroll
            for (int c = 0; c < CC; ++c)
                acc = fmaf(xs[(tt + k) * CC + c], wsm[(k * CC + c) * FF + f], acc);
        float e = __expf(fmaf(acc, s, bbv));
        float ang = (float)(t0 + tt) * tsf;
        float p = (f & 1) ? cosf(ang) : sinf(ang);
        packed[i] = packsplit(fmaf(e, inv_se, p));
    }
    __syncthreads();   // all conv reads of xs/wsm complete -> safe to overwrite
#pragma unroll
    for (int i = 0; i < 32; ++i) Asp[(tq + 4 * i) * 68 + f] = packed[i];
    __syncthreads();   // Asp visible

    const int lane = tid & 63;
    const int wv   = tid >> 6;
    const int half = lane >> 5;
    const int ln31 = lane & 31;

    for (int lt = lt0; lt < lt0 + 16; ++lt) {
        const int lbase = lt * 128 + wv * 32;
        const uint32_t* wp = Wt + (size_t)(lbase + ln31) * 64 + half * 8;
        uint4 wr[8];
#pragma unroll
        for (int kf = 0; kf < 4; ++kf) {
            wr[kf * 2]     = *reinterpret_cast<const uint4*>(wp + kf * 16);
            wr[kf * 2 + 1] = *reinterpret_cast<const uint4*>(wp + kf * 16 + 4);
        }
        short8 Whi[4], Wlo[4];
#pragma unroll
        for (int kf = 0; kf < 4; ++kf) {
            Whi[kf] = mk_hi(wr[kf * 2], wr[kf * 2 + 1]);
            Wlo[kf] = mk_lo(wr[kf * 2], wr[kf * 2 + 1]);
        }
        float dbv[16], sumsig[16];
#pragma unroll
        for (int r = 0; r < 16; ++r) {
            dbv[r] = db[lbase + 4 * half + (r & 3) + 8 * (r >> 2)];
            sumsig[r] = 0.f;
        }
        for (int nt = 0; nt < 4; ++nt) {
            floatx16 acc;
#pragma unroll
            for (int r = 0; r < 16; ++r) acc[r] = dbv[r];   // bias folded into C-init
            const uint32_t* ap = Asp + (nt * 32 + ln31) * 68 + half * 8;
#pragma unroll
            for (int kf = 0; kf < 4; ++kf) {
                uint4 q0 = *reinterpret_cast<const uint4*>(ap + kf * 16);
                uint4 q1 = *reinterpret_cast<const uint4*>(ap + kf * 16 + 4);
                short8 Bhi = mk_hi(q0, q1);
                short8 Blo = mk_lo(q0, q1);
                acc = __builtin_amdgcn_mfma_f32_32x32x16_bf16(Whi[kf], Bhi, acc, 0, 0, 0);
                acc = __builtin_amdgcn_mfma_f32_32x32x16_bf16(Whi[kf], Blo, acc, 0, 0, 0);
                acc = __builtin_amdgcn_mfma_f32_32x32x16_bf16(Wlo[kf], Bhi, acc, 0, 0, 0);
            }
#pragma unroll
            for (int r = 0; r < 16; ++r) {
                float e = __expf(-acc[r]);
                sumsig[r] += __builtin_amdgcn_rcpf(1.0f + e);   // sigma(z+db)
            }
        }
#pragma unroll
        for (int r = 0; r < 16; ++r) {
            float v = sumsig[r];
            v += __shfl_xor(v, 1, 32);
            v += __shfl_xor(v, 2, 32);
            v += __shfl_xor(v, 4, 32);
            v += __shfl_xor(v, 8, 32);
            v += __shfl_xor(v, 16, 32);
            sumsig[r] = v;
        }
        if (ln31 == 0) {
            float* dst = shiftsum + (size_t)b * LL + lbase + 4 * half;
#pragma unroll
            for (int r = 0; r < 16; ++r)
                atomicAdd(dst + (r & 3) + 8 * (r >> 2), sumsig[r]);
        }
    }
}

// ------- Kernel 3: truncated Gaussian warp (shift = 2*S - T) -----------------------
__global__ __launch_bounds__(256) void k_warp(
        const float* __restrict__ shiftsum, const float* __restrict__ x,
        float* __restrict__ out) {
    const int idx = blockIdx.x * 256 + threadIdx.x;  // = b*L + l
    const int l = idx & (LL - 1);
    const int b = idx >> 12;
    const float sh = fmaf(2.0f, shiftsum[idx], -(float)TT);
    const float scale = (float)TT / (float)LL;
    const float center = ((float)(l + 1) + sh) * scale;
    const float R = 7.0f;
    int tlo = (int)ceilf(center - 1.0f - R);
    int thi = (int)floorf(center - 1.0f + R);
    if (tlo < 0) tlo = 0;
    if (thi > TT - 1) thi = TT - 1;
    float acc[CC];
#pragma unroll
    for (int c = 0; c < CC; ++c) acc[c] = 0.f;
    const float inv_amp = (float)(1.0 / 1.772637204826652);
    for (int t = tlo; t <= thi; ++t) {
        float d = (float)(t + 1) - center;
        float w = __expf(-d * d) * inv_amp;   // WIDTH = 1
        const float4 x0 = *reinterpret_cast<const float4*>(x + ((size_t)b * TT + t) * CC);
        const float4 x1 = *reinterpret_cast<const float4*>(x + ((size_t)b * TT + t) * CC + 4);
        acc[0] = fmaf(w, x0.x, acc[0]);
        acc[1] = fmaf(w, x0.y, acc[1]);
        acc[2] = fmaf(w, x0.z, acc[2]);
        acc[3] = fmaf(w, x0.w, acc[3]);
        acc[4] = fmaf(w, x1.x, acc[4]);
        acc[5] = fmaf(w, x1.y, acc[5]);
        acc[6] = fmaf(w, x1.z, acc[6]);
        acc[7] = fmaf(w, x1.w, acc[7]);
    }
    float* o = out + (size_t)idx * CC;
    *reinterpret_cast<float4*>(o)     = make_float4(acc[0], acc[1], acc[2], acc[3]);
    *reinterpret_cast<float4*>(o + 4) = make_float4(acc[4], acc[5], acc[6], acc[7]);
}

extern "C" void kernel_launch(void* const* d_in, const int* in_sizes, int n_in,
                              void* d_out, int out_size, void* d_ws, size_t ws_size,
                              hipStream_t stream) {
    const float* x  = (const float*)d_in[0];
    const float* cw = (const float*)d_in[1];
    const float* cb = (const float*)d_in[2];
    const float* gm = (const float*)d_in[3];
    const float* bt = (const float*)d_in[4];
    const float* mn = (const float*)d_in[5];
    const float* vr = (const float*)d_in[6];
    const float* dw = (const float*)d_in[7];
    const float* db = (const float*)d_in[8];

    float* sumexp    = (float*)d_ws;                       // 1024 floats
    float* shiftsum  = sumexp + BB * FF;                   // 65536 floats
    uint32_t* Wt     = (uint32_t*)(shiftsum + BB * LL);    // 262144 dwords (1 MB)

    hipMemsetAsync(sumexp, 0, (size_t)(BB * FF + BB * LL) * sizeof(float), stream);

    k_split<<<(FF * LL) / 256, 256, 0, stream>>>(dw, Wt);
    k_sumexp<<<BB * (TT / 64), 256, 0, stream>>>(x, cw, cb, gm, bt, mn, vr, sumexp);
    k_main<<<dim3(TT / 128, BB, 2), 256, 0, stream>>>(x, cw, cb, gm, bt, mn, vr,
                                                      Wt, db, sumexp, shiftsum);
    k_warp<<<(BB * LL) / 256, 256, 0, stream>>>(shiftsum, x, (float*)d_out);
}

// Round 8
// 397.963 us; speedup vs baseline: 6.0450x; 1.6880x over previous
//
#include <hip/hip_runtime.h>
#include <hip/hip_fp16.h>
#include <stdint.h>

#define BB 16
#define TT 4096
#define CC 8
#define FF 64
#define KW 11
#define LL 4096

typedef __attribute__((ext_vector_type(8))) short short8;
typedef __attribute__((ext_vector_type(16))) float floatx16;

__device__ __forceinline__ unsigned short f2b(float f) {
    union { float f; uint32_t i; } v; v.f = f;
    uint32_t x = v.i;
    return (unsigned short)((x + 0x7fffu + ((x >> 16) & 1u)) >> 16);  // RNE
}
__device__ __forceinline__ float b2f(unsigned short u) {
    union { uint32_t i; float f; } v; v.i = ((uint32_t)u) << 16; return v.f;
}
// pack fp32 -> (hi bf16 in low16) | (residual-lo bf16 in high16)
__device__ __forceinline__ uint32_t packsplit(float v) {
    unsigned short hi = f2b(v);
    unsigned short lo = f2b(v - b2f(hi));
    return (uint32_t)hi | ((uint32_t)lo << 16);
}
__device__ __forceinline__ short8 mk8(uint32_t a, uint32_t b, uint32_t c, uint32_t d) {
    union { uint32_t u[4]; short8 s; } r;
    r.u[0] = a; r.u[1] = b; r.u[2] = c; r.u[3] = d; return r.s;
}
__device__ __forceinline__ short8 mk_hi(uint4 q0, uint4 q1) {
    return mk8((q0.x & 0xffffu) | (q0.y << 16), (q0.z & 0xffffu) | (q0.w << 16),
               (q1.x & 0xffffu) | (q1.y << 16), (q1.z & 0xffffu) | (q1.w << 16));
}
__device__ __forceinline__ short8 mk_lo(uint4 q0, uint4 q1) {
    return mk8((q0.x >> 16) | (q0.y & 0xffff0000u), (q0.z >> 16) | (q0.w & 0xffff0000u),
               (q1.x >> 16) | (q1.y & 0xffff0000u), (q1.z >> 16) | (q1.w & 0xffff0000u));
}

// ------- Kernel 0: W fp32 [64][4096] -> packed hi/lo bf16, transposed [l][k] -------
__global__ __launch_bounds__(256) void k_split(
        const float* __restrict__ dw, uint32_t* __restrict__ Wt) {
    const int idx = blockIdx.x * 256 + threadIdx.x;   // 262144
    const int k = idx >> 12, l = idx & (LL - 1);
    Wt[l * 64 + k] = packsplit(dw[idx]);
}

// ------- Kernel 1: conv1d + BN + exp -> sumexp[b,f] --------------------------------
__global__ __launch_bounds__(256) void k_sumexp(
        const float* __restrict__ x, const float* __restrict__ cw,
        const float* __restrict__ cb, const float* __restrict__ gm,
        const float* __restrict__ bt, const float* __restrict__ mn,
        const float* __restrict__ vr, float* __restrict__ sumexp) {
    __shared__ float wsm[KW * CC * FF];
    __shared__ float xs[(64 + KW - 1) * CC];
    __shared__ float red[4 * FF];
    const int tid = threadIdx.x;
    const int b  = blockIdx.x / (TT / 64);
    const int t0 = (blockIdx.x % (TT / 64)) * 64;

    for (int i = tid; i < KW * CC * FF; i += 256) wsm[i] = cw[i];
    for (int i = tid; i < (64 + KW - 1) * CC; i += 256) {
        int row = i / CC, c = i % CC;
        int t = t0 - (KW / 2) + row;
        xs[i] = (t >= 0 && t < TT) ? x[((size_t)b * TT + t) * CC + c] : 0.0f;
    }
    const int f = tid & 63, ts = tid >> 6;
    const float s  = gm[f] * rsqrtf(vr[f] + 1e-3f);
    const float bb = bt[f] + (cb[f] - mn[f]) * s;
    __syncthreads();

    float esum = 0.f;
    for (int tt = ts; tt < 64; tt += 4) {
        float acc = 0.f;
#pragma unroll
        for (int k = 0; k < KW; ++k)
#pragma unroll
            for (int c = 0; c < CC; ++c)
                acc = fmaf(xs[(tt + k) * CC + c], wsm[(k * CC + c) * FF + f], acc);
        esum += __expf(fmaf(acc, s, bb));
    }
    red[ts * FF + f] = esum;
    __syncthreads();
    if (ts == 0) {
        float tot = red[f] + red[FF + f] + red[2 * FF + f] + red[3 * FF + f];
        atomicAdd(&sumexp[b * FF + f], tot);
    }
}

// ------- Kernel 2: conv+softmax+pos -> split-bf16 MFMA GEMM -> sigma-sum -----------
// Round-4 codegen shape exactly: rolled conv loop writing straight to LDS, separate
// LDS regions (NO union, NO register staging buffer, NO unroll pragma on conv).
// LDS cut 78.3->50.5 KB (dbs dropped -> db read from global per lt; conv weights
// stored fp16 -- softmax entries ~1/4096 so fp16 weight error is ~2e-7 abs on h2).
// 50496 B -> 3 blocks/CU. Grid z-split: 1024 blocks, 16 l-tiles each.
__global__ __launch_bounds__(256) void k_main(
        const float* __restrict__ x,  const float* __restrict__ cw,
        const float* __restrict__ cb, const float* __restrict__ gm,
        const float* __restrict__ bt, const float* __restrict__ mn,
        const float* __restrict__ vr, const uint32_t* __restrict__ Wt,
        const float* __restrict__ db, const float* __restrict__ sumexp,
        float* __restrict__ shiftsum) {
    __shared__ uint32_t Asp[128 * 68];            // 34816 B, Asp[t][f]
    __shared__ float xs[(128 + KW - 1) * CC];     // 4416 B
    __shared__ __half wsh[KW * CC * FF];          // 11264 B

    const int tid = threadIdx.x;
    const int b   = blockIdx.y;
    const int t0  = blockIdx.x * 128;
    const int lt0 = blockIdx.z * 16;

    for (int i = tid; i < KW * CC * FF; i += 256) wsh[i] = __float2half(cw[i]);
    for (int i = tid; i < (128 + KW - 1) * CC; i += 256) {
        int row = i / CC, c = i % CC;
        int t = t0 - (KW / 2) + row;
        xs[i] = (t >= 0 && t < TT) ? x[((size_t)b * TT + t) * CC + c] : 0.0f;
    }
    const int f = tid & 63, tq = tid >> 6;
    const float s  = gm[f] * rsqrtf(vr[f] + 1e-3f);
    const float bbv = bt[f] + (cb[f] - mn[f]) * s;
    const float inv_se = 1.0f / sumexp[b * FF + f];
    const float tsf = exp2f(-0.20762050586796017f * (float)(f & ~1));
    __syncthreads();

    // rolled loop, direct LDS write (round-4 codegen shape: ~124 VGPR, no spill)
    for (int tt = tq; tt < 128; tt += 4) {
        float acc = 0.f;
#pragma unroll
        for (int k = 0; k < KW; ++k)
#pragma unroll
            for (int c = 0; c < CC; ++c)
                acc = fmaf(xs[(tt + k) * CC + c],
                           __half2float(wsh[(k * CC + c) * FF + f]), acc);
        float e = __expf(fmaf(acc, s, bbv));
        float ang = (float)(t0 + tt) * tsf;
        float p = (f & 1) ? cosf(ang) : sinf(ang);
        Asp[tt * 68 + f] = packsplit(fmaf(e, inv_se, p));
    }
    __syncthreads();

    const int lane = tid & 63;
    const int wv   = tid >> 6;
    const int half = lane >> 5;
    const int ln31 = lane & 31;

    for (int lt = lt0; lt < lt0 + 16; ++lt) {
        const int lbase = lt * 128 + wv * 32;
        const uint32_t* wp = Wt + (size_t)(lbase + ln31) * 64 + half * 8;
        uint4 wr[8];
#pragma unroll
        for (int kf = 0; kf < 4; ++kf) {
            wr[kf * 2]     = *reinterpret_cast<const uint4*>(wp + kf * 16);
            wr[kf * 2 + 1] = *reinterpret_cast<const uint4*>(wp + kf * 16 + 4);
        }
        short8 Whi[4], Wlo[4];
#pragma unroll
        for (int kf = 0; kf < 4; ++kf) {
            Whi[kf] = mk_hi(wr[kf * 2], wr[kf * 2 + 1]);
            Wlo[kf] = mk_lo(wr[kf * 2], wr[kf * 2 + 1]);
        }
        float dbv[16], sumsig[16];
#pragma unroll
        for (int r = 0; r < 16; ++r) {
            dbv[r] = db[lbase + 4 * half + (r & 3) + 8 * (r >> 2)];
            sumsig[r] = 0.f;
        }
        for (int nt = 0; nt < 4; ++nt) {
            floatx16 acc = {0.f, 0.f, 0.f, 0.f, 0.f, 0.f, 0.f, 0.f,
                            0.f, 0.f, 0.f, 0.f, 0.f, 0.f, 0.f, 0.f};
            const uint32_t* ap = Asp + (nt * 32 + ln31) * 68 + half * 8;
#pragma unroll
            for (int kf = 0; kf < 4; ++kf) {
                uint4 q0 = *reinterpret_cast<const uint4*>(ap + kf * 16);
                uint4 q1 = *reinterpret_cast<const uint4*>(ap + kf * 16 + 4);
                short8 Bhi = mk_hi(q0, q1);
                short8 Blo = mk_lo(q0, q1);
                acc = __builtin_amdgcn_mfma_f32_32x32x16_bf16(Whi[kf], Bhi, acc, 0, 0, 0);
                acc = __builtin_amdgcn_mfma_f32_32x32x16_bf16(Whi[kf], Blo, acc, 0, 0, 0);
                acc = __builtin_amdgcn_mfma_f32_32x32x16_bf16(Wlo[kf], Bhi, acc, 0, 0, 0);
            }
#pragma unroll
            for (int r = 0; r < 16; ++r) {
                float z = acc[r] + dbv[r];
                float e = __expf(-z);
                sumsig[r] += __builtin_amdgcn_rcpf(1.0f + e);   // sigma(z)
            }
        }
#pragma unroll
        for (int r = 0; r < 16; ++r) {
            float v = sumsig[r];
            v += __shfl_xor(v, 1, 32);
            v += __shfl_xor(v, 2, 32);
            v += __shfl_xor(v, 4, 32);
            v += __shfl_xor(v, 8, 32);
            v += __shfl_xor(v, 16, 32);
            sumsig[r] = v;
        }
        if (ln31 == 0) {
            float* dst = shiftsum + (size_t)b * LL + lbase + 4 * half;
#pragma unroll
            for (int r = 0; r < 16; ++r)
                atomicAdd(dst + (r & 3) + 8 * (r >> 2), sumsig[r]);
        }
    }
}

// ------- Kernel 3: truncated Gaussian warp (shift = 2*S - T) -----------------------
__global__ __launch_bounds__(256) void k_warp(
        const float* __restrict__ shiftsum, const float* __restrict__ x,
        float* __restrict__ out) {
    const int idx = blockIdx.x * 256 + threadIdx.x;  // = b*L + l
    const int l = idx & (LL - 1);
    const int b = idx >> 12;
    const float sh = fmaf(2.0f, shiftsum[idx], -(float)TT);
    const float scale = (float)TT / (float)LL;
    const float center = ((float)(l + 1) + sh) * scale;
    const float R = 7.0f;
    int tlo = (int)ceilf(center - 1.0f - R);
    int thi = (int)floorf(center - 1.0f + R);
    if (tlo < 0) tlo = 0;
    if (thi > TT - 1) thi = TT - 1;
    float acc[CC];
#pragma unroll
    for (int c = 0; c < CC; ++c) acc[c] = 0.f;
    const float inv_amp = (float)(1.0 / 1.772637204826652);
    for (int t = tlo; t <= thi; ++t) {
        float d = (float)(t + 1) - center;
        float w = __expf(-d * d) * inv_amp;   // WIDTH = 1
        const float4 x0 = *reinterpret_cast<const float4*>(x + ((size_t)b * TT + t) * CC);
        const float4 x1 = *reinterpret_cast<const float4*>(x + ((size_t)b * TT + t) * CC + 4);
        acc[0] = fmaf(w, x0.x, acc[0]);
        acc[1] = fmaf(w, x0.y, acc[1]);
        acc[2] = fmaf(w, x0.z, acc[2]);
        acc[3] = fmaf(w, x0.w, acc[3]);
        acc[4] = fmaf(w, x1.x, acc[4]);
        acc[5] = fmaf(w, x1.y, acc[5]);
        acc[6] = fmaf(w, x1.z, acc[6]);
        acc[7] = fmaf(w, x1.w, acc[7]);
    }
    float* o = out + (size_t)idx * CC;
    *reinterpret_cast<float4*>(o)     = make_float4(acc[0], acc[1], acc[2], acc[3]);
    *reinterpret_cast<float4*>(o + 4) = make_float4(acc[4], acc[5], acc[6], acc[7]);
}

extern "C" void kernel_launch(void* const* d_in, const int* in_sizes, int n_in,
                              void* d_out, int out_size, void* d_ws, size_t ws_size,
                              hipStream_t stream) {
    const float* x  = (const float*)d_in[0];
    const float* cw = (const float*)d_in[1];
    const float* cb = (const float*)d_in[2];
    const float* gm = (const float*)d_in[3];
    const float* bt = (const float*)d_in[4];
    const float* mn = (const float*)d_in[5];
    const float* vr = (const float*)d_in[6];
    const float* dw = (const float*)d_in[7];
    const float* db = (const float*)d_in[8];

    float* sumexp    = (float*)d_ws;                       // 1024 floats
    float* shiftsum  = sumexp + BB * FF;                   // 65536 floats
    uint32_t* Wt     = (uint32_t*)(shiftsum + BB * LL);    // 262144 dwords (1 MB)

    hipMemsetAsync(sumexp, 0, (size_t)(BB * FF + BB * LL) * sizeof(float), stream);

    k_split<<<(FF * LL) / 256, 256, 0, stream>>>(dw, Wt);
    k_sumexp<<<BB * (TT / 64), 256, 0, stream>>>(x, cw, cb, gm, bt, mn, vr, sumexp);
    k_main<<<dim3(TT / 128, BB, 2), 256, 0, stream>>>(x, cw, cb, gm, bt, mn, vr,
                                                      Wt, db, sumexp, shiftsum);
    k_warp<<<(BB * LL) / 256, 256, 0, stream>>>(shiftsum, x, (float*)d_out);
}